// Round 2
// baseline (2632.178 us; speedup 1.0000x reference)
//
#include <hip/hip_runtime.h>

#define HH 128
#define GG 256

using f32x4  = __attribute__((ext_vector_type(4))) float;
using bf16x8 = __attribute__((ext_vector_type(8))) __bf16;

// ---------------------------------------------------------------- setup
__global__ __launch_bounds__(256) void setup_k(const float* __restrict__ x,
                                               float* __restrict__ z0,
                                               float* __restrict__ pooled, int n)
{
    int i = blockIdx.x * 256 + threadIdx.x;
    if (i < GG * HH) pooled[i] = 0.f;
    if (i < n) z0[i] = x[i];
}

// ------------------------------------------------- layer0 scalar edge agg
__global__ __launch_bounds__(256) void edge0_k(const float* __restrict__ x,
                                               const int* __restrict__ src,
                                               const int* __restrict__ dst,
                                               float* __restrict__ z0, int ne)
{
    int e = blockIdx.x * 256 + threadIdx.x;
    if (e < ne) unsafeAtomicAdd(&z0[dst[e]], x[src[e]]);
}

// ------------------------------------------------- dense edge aggregation
// z[dst] += h[src], float4 per thread (32 threads per edge)
__global__ __launch_bounds__(256) void edge_add4_k(const float* __restrict__ h,
                                                   const int* __restrict__ src,
                                                   const int* __restrict__ dst,
                                                   float* __restrict__ z, int total)
{
    int stride = gridDim.x * 256;
    for (int i = blockIdx.x * 256 + threadIdx.x; i < total; i += stride) {
        const int e = i >> 5, q = (i & 31) * 4;
        const float4 v = *(const float4*)&h[(size_t)src[e] * HH + q];
        float* zp = &z[(size_t)dst[e] * HH + q];
        unsafeAtomicAdd(zp + 0, v.x);
        unsafeAtomicAdd(zp + 1, v.y);
        unsafeAtomicAdd(zp + 2, v.z);
        unsafeAtomicAdd(zp + 3, v.w);
    }
}

// ------------------------------------------------------------- MFMA GEMM
// out[n][c] = epi(bias[c] + sum_j A[n][j] * W[j][c]),  A: M x 128, W: 128 x 128
// AMODE 0: A read from `in` (fp32 [M,128]);  AMODE 1: A[n][j] = relu(in[n]*W1[j]+b1[j])
// 256 threads = 4 waves; wave w owns cols [w*32, w*32+32). 16-row tiles.
// W held entirely in registers as bf16 fragments. No LDS.
// mfma_f32_16x16x32_bf16 layouts: A row=lane&15,k=(lane>>4)*8+j ;
// B col=lane&15,k=(lane>>4)*8+j ; D col=lane&15,row=(lane>>4)*4+r.
template<int AMODE, int ORELU, int WRITE2, int POOL>
__global__ __launch_bounds__(256) void gemm_mfma_k(
    const float* __restrict__ in,
    const float* __restrict__ W1, const float* __restrict__ b1,
    const float* __restrict__ W,  const float* __restrict__ bias,
    float* __restrict__ out, float* __restrict__ out2,
    const int* __restrict__ batch, float* __restrict__ pooled,
    int ntiles)
{
    const int lane = threadIdx.x & 63;
    const int wv   = threadIdx.x >> 6;     // col group 0..3
    const int l16  = lane & 15;
    const int lq   = lane >> 4;            // 0..3
    const int colbase = wv * 32;

    // preload W fragments (bf16) : wf[kb][nb]
    bf16x8 wf[4][2];
    #pragma unroll
    for (int kb = 0; kb < 4; ++kb)
        #pragma unroll
        for (int nb = 0; nb < 2; ++nb) {
            const int col = colbase + nb * 16 + l16;
            const int k0  = kb * 32 + lq * 8;
            bf16x8 t;
            #pragma unroll
            for (int j = 0; j < 8; ++j) t[j] = (__bf16)W[(k0 + j) * HH + col];
            wf[kb][nb] = t;
        }
    const float bs0 = bias[colbase + l16];
    const float bs1 = bias[colbase + 16 + l16];

    // layer-0 expand coefficients (per-lane slice of W1/b1)
    float w1f[32], b1f[32];
    if (AMODE == 1) {
        #pragma unroll
        for (int kb = 0; kb < 4; ++kb)
            #pragma unroll
            for (int j = 0; j < 8; ++j) {
                w1f[kb * 8 + j] = W1[kb * 32 + lq * 8 + j];
                b1f[kb * 8 + j] = b1[kb * 32 + lq * 8 + j];
            }
    }

    for (int tile = blockIdx.x; tile < ntiles; tile += gridDim.x) {
        const int r0 = tile * 16;

        // ---- build A fragments (registers only)
        bf16x8 af[4];
        if (AMODE == 0) {
            const float* arow = in + (size_t)(r0 + l16) * HH;
            #pragma unroll
            for (int kb = 0; kb < 4; ++kb) {
                const float4 lo = *(const float4*)(arow + kb * 32 + lq * 8);
                const float4 hi = *(const float4*)(arow + kb * 32 + lq * 8 + 4);
                bf16x8 t;
                t[0] = (__bf16)lo.x; t[1] = (__bf16)lo.y; t[2] = (__bf16)lo.z; t[3] = (__bf16)lo.w;
                t[4] = (__bf16)hi.x; t[5] = (__bf16)hi.y; t[6] = (__bf16)hi.z; t[7] = (__bf16)hi.w;
                af[kb] = t;
            }
        } else {
            const float s = in[r0 + l16];
            #pragma unroll
            for (int kb = 0; kb < 4; ++kb) {
                bf16x8 t;
                #pragma unroll
                for (int j = 0; j < 8; ++j)
                    t[j] = (__bf16)fmaxf(fmaf(s, w1f[kb * 8 + j], b1f[kb * 8 + j]), 0.f);
                af[kb] = t;
            }
        }

        // in-place safety (gemm2 reads h rows then overwrites them):
        // all 4 waves finish A-loads of this tile before any store
        if (WRITE2) __syncthreads();

        f32x4 acc0 = (f32x4){bs0, bs0, bs0, bs0};
        f32x4 acc1 = (f32x4){bs1, bs1, bs1, bs1};
        #pragma unroll
        for (int kb = 0; kb < 4; ++kb) {
            acc0 = __builtin_amdgcn_mfma_f32_16x16x32_bf16(af[kb], wf[kb][0], acc0, 0, 0, 0);
            acc1 = __builtin_amdgcn_mfma_f32_16x16x32_bf16(af[kb], wf[kb][1], acc1, 0, 0, 0);
        }

        // ---- epilogue
        #pragma unroll
        for (int r = 0; r < 4; ++r) {
            const int row = r0 + lq * 4 + r;
            float v0 = acc0[r], v1 = acc1[r];
            if (ORELU) { v0 = fmaxf(v0, 0.f); v1 = fmaxf(v1, 0.f); }
            if (POOL) {
                const int g = batch[row];
                float* p = &pooled[(size_t)g * HH + colbase + l16];
                unsafeAtomicAdd(p, v0);
                unsafeAtomicAdd(p + 16, v1);
            } else {
                float* po = &out[(size_t)row * HH + colbase + l16];
                po[0] = v0; po[16] = v1;
                if (WRITE2) {
                    float* p2 = &out2[(size_t)row * HH + colbase + l16];
                    p2[0] = v0; p2[16] = v1;
                }
            }
        }
    }
}

// ---------------------------------------------------------------- final FC
__global__ __launch_bounds__(128) void fc_k(const float* __restrict__ pooled,
                                            const float* __restrict__ Wfc,
                                            const float* __restrict__ bfc,
                                            float* __restrict__ out)
{
    __shared__ float p[HH];
    const int g = blockIdx.x, k = threadIdx.x;
    p[k] = pooled[g * HH + k];
    __syncthreads();
    float acc = bfc[k];
    #pragma unroll 8
    for (int j = 0; j < HH; ++j) acc = fmaf(p[j], Wfc[j * HH + k], acc);
    out[g * HH + k] = acc;
}

extern "C" void kernel_launch(void* const* d_in, const int* in_sizes, int n_in,
                              void* d_out, int out_size, void* d_ws, size_t ws_size,
                              hipStream_t stream)
{
    const float* x     = (const float*)d_in[0];
    const int*   ei    = (const int*)d_in[1];
    const int*   batch = (const int*)d_in[2];
    const float* W1_0 = (const float*)d_in[3];
    const float* b1_0 = (const float*)d_in[4];
    const float* W2_0 = (const float*)d_in[5];
    const float* b2_0 = (const float*)d_in[6];
    const float* W1_1 = (const float*)d_in[7];
    const float* b1_1 = (const float*)d_in[8];
    const float* W2_1 = (const float*)d_in[9];
    const float* b2_1 = (const float*)d_in[10];
    const float* W1_2 = (const float*)d_in[11];
    const float* b1_2 = (const float*)d_in[12];
    const float* W2_2 = (const float*)d_in[13];
    const float* b2_2 = (const float*)d_in[14];
    const float* Wfc  = (const float*)d_in[15];
    const float* bfc  = (const float*)d_in[16];

    const int N = in_sizes[0];          // 100000
    const int E = in_sizes[1] / 2;      // 640000
    const int* src = ei;
    const int* dst = ei + E;
    const int ntiles = N / 16;          // 6250, exact

    float* z      = (float*)d_ws;                 // [N,128]
    float* h      = z + (size_t)N * HH;           // [N,128]
    float* z0     = h + (size_t)N * HH;           // [N]
    float* pooled = z0 + N;                       // [G,128]
    float* outp   = (float*)d_out;

    // layer 0: z0 = x + scatter(x)   (scalar input dim)
    setup_k<<<(N + 255) / 256, 256, 0, stream>>>(x, z0, pooled, N);
    edge0_k<<<(E + 255) / 256, 256, 0, stream>>>(x, src, dst, z0, E);
    // layer 0 MLP fused: h,z <- relu(z0 (x) W1_0 + b1_0) @ W2_0 + b2_0
    gemm_mfma_k<1, 0, 1, 0><<<1024, 256, 0, stream>>>(
        z0, W1_0, b1_0, W2_0, b2_0, h, z, nullptr, nullptr, ntiles);

    // layer 1
    edge_add4_k<<<2048, 256, 0, stream>>>(h, src, dst, z, E * 32);
    gemm_mfma_k<0, 1, 0, 0><<<1024, 256, 0, stream>>>(
        z, nullptr, nullptr, W1_1, b1_1, h, nullptr, nullptr, nullptr, ntiles);
    gemm_mfma_k<0, 0, 1, 0><<<1024, 256, 0, stream>>>(
        h, nullptr, nullptr, W2_1, b2_1, h, z, nullptr, nullptr, ntiles);

    // layer 2 (pool fused into second GEMM)
    edge_add4_k<<<2048, 256, 0, stream>>>(h, src, dst, z, E * 32);
    gemm_mfma_k<0, 1, 0, 0><<<1024, 256, 0, stream>>>(
        z, nullptr, nullptr, W1_2, b1_2, h, nullptr, nullptr, nullptr, ntiles);
    gemm_mfma_k<0, 0, 0, 1><<<1024, 256, 0, stream>>>(
        h, nullptr, nullptr, W2_2, b2_2, nullptr, nullptr, batch, pooled, ntiles);

    // final FC
    fc_k<<<GG, HH, 0, stream>>>(pooled, Wfc, bfc, outp);
}

// Round 3
// 667.107 us; speedup vs baseline: 3.9457x; 3.9457x over previous
//
#include <hip/hip_runtime.h>

#define HH 128
#define GG 256
#define SB 1024

using f32x4  = __attribute__((ext_vector_type(4))) float;
using bf16x8 = __attribute__((ext_vector_type(8))) __bf16;

// ---------------------------------------------------------------- zero
__global__ __launch_bounds__(256) void zero_k(int* __restrict__ cnt,
                                              float* __restrict__ pooled, int n)
{
    int i = blockIdx.x * 256 + threadIdx.x;
    if (i < n) cnt[i] = 0;
    if (i < GG * HH) pooled[i] = 0.f;
}

// ---------------------------------------------------------------- CSR build
__global__ __launch_bounds__(256) void count_k(const int* __restrict__ dst,
                                               int* __restrict__ cnt, int ne)
{
    int e = blockIdx.x * 256 + threadIdx.x;
    if (e < ne) atomicAdd(&cnt[dst[e]], 1);
}

__global__ __launch_bounds__(SB) void scan1_k(const int* __restrict__ cnt,
                                              int* __restrict__ rowptr,
                                              int* __restrict__ partial, int n)
{
    __shared__ int s[SB];
    const int t = threadIdx.x, g = blockIdx.x * SB + t;
    const int v = (g < n) ? cnt[g] : 0;
    s[t] = v; __syncthreads();
    for (int off = 1; off < SB; off <<= 1) {
        int a = (t >= off) ? s[t - off] : 0; __syncthreads();
        s[t] += a; __syncthreads();
    }
    if (g < n) rowptr[g] = s[t] - v;            // exclusive within block
    if (t == SB - 1) partial[blockIdx.x] = s[t]; // block total
}

__global__ __launch_bounds__(128) void scan2_k(int* __restrict__ partial, int nb)
{
    __shared__ int s[128];
    const int t = threadIdx.x;
    const int v = (t < nb) ? partial[t] : 0;
    s[t] = v; __syncthreads();
    for (int off = 1; off < 128; off <<= 1) {
        int a = (t >= off) ? s[t - off] : 0; __syncthreads();
        s[t] += a; __syncthreads();
    }
    if (t < nb) partial[t] = s[t] - v;          // exclusive block offsets
}

__global__ __launch_bounds__(SB) void scan3_k(int* __restrict__ rowptr,
                                              const int* __restrict__ partial,
                                              int n, int ne)
{
    int g = blockIdx.x * SB + threadIdx.x;
    if (g < n) rowptr[g] += partial[blockIdx.x];
    if (g == n - 1) rowptr[n] = ne;
}

// countdown-scatter: consumes cnt (ends all-zero), fills eidx with src ids
__global__ __launch_bounds__(256) void scatter_k(const int* __restrict__ src,
                                                 const int* __restrict__ dst,
                                                 const int* __restrict__ rowptr,
                                                 int* __restrict__ cnt,
                                                 int* __restrict__ eidx, int ne)
{
    int e = blockIdx.x * 256 + threadIdx.x;
    if (e < ne) {
        const int d = dst[e];
        const int off = atomicSub(&cnt[d], 1) - 1;
        eidx[rowptr[d] + off] = src[e];
    }
}

// ------------------------------------------- layer0 scalar pull aggregation
__global__ __launch_bounds__(256) void agg0_k(const float* __restrict__ x,
                                              const int* __restrict__ rowptr,
                                              const int* __restrict__ eidx,
                                              float* __restrict__ z0, int n)
{
    int i = blockIdx.x * 256 + threadIdx.x;
    if (i < n) {
        float s = x[i];
        const int e = rowptr[i + 1];
        for (int j = rowptr[i]; j < e; ++j) s += x[eidx[j]];
        z0[i] = s;
    }
}

// ------------------------------------------- dense pull aggregation
// z[n][:] = h[n][:] + sum_{s in in(n)} h[s][:]   (wave per node, float2/lane)
__global__ __launch_bounds__(256) void aggw_k(const float* __restrict__ h,
                                              const int* __restrict__ rowptr,
                                              const int* __restrict__ eidx,
                                              float* __restrict__ z, int n)
{
    const int gw   = (blockIdx.x * 256 + threadIdx.x) >> 6;
    const int lane = threadIdx.x & 63;
    const int nw   = (gridDim.x * 256) >> 6;
    const float2* h2 = (const float2*)h;
    float2* z2 = (float2*)z;

    for (int node = gw; node < n; node += nw) {
        const int b = rowptr[node], e = rowptr[node + 1];
        float2 a0 = h2[(size_t)node * 64 + lane];
        float2 a1 = make_float2(0.f, 0.f);
        int j = b;
        for (; j + 1 < e; j += 2) {
            const int s0 = eidx[j], s1 = eidx[j + 1];
            const float2 v0 = h2[(size_t)s0 * 64 + lane];
            const float2 v1 = h2[(size_t)s1 * 64 + lane];
            a0.x += v0.x; a0.y += v0.y;
            a1.x += v1.x; a1.y += v1.y;
        }
        if (j < e) {
            const float2 v = h2[(size_t)eidx[j] * 64 + lane];
            a0.x += v.x; a0.y += v.y;
        }
        z2[(size_t)node * 64 + lane] = make_float2(a0.x + a1.x, a0.y + a1.y);
    }
}

// ------------------------------------------------------------- MFMA GEMM
// out[n][c] = epi(bias[c] + sum_j A[n][j] * W[j][c]),  W: 128x128 in registers
// AMODE 0: A = in (fp32 [M,128]);  AMODE 1: A[n][j] = relu(in[n]*W1[j]+b1[j])
// SYNC 1: in-place safe (barrier between A-load and store)
// mfma_f32_16x16x32_bf16: A row=lane&15,k=(lane>>4)*8+j ;
// B col=lane&15,k=(lane>>4)*8+j ; D col=lane&15,row=(lane>>4)*4+r.
template<int AMODE, int ORELU, int POOL, int SYNC>
__global__ __launch_bounds__(256) void gemm_mfma_k(
    const float* __restrict__ in,
    const float* __restrict__ W1, const float* __restrict__ b1,
    const float* __restrict__ W,  const float* __restrict__ bias,
    float* __restrict__ out,
    const int* __restrict__ batch, float* __restrict__ pooled,
    int ntiles)
{
    const int lane = threadIdx.x & 63;
    const int wv   = threadIdx.x >> 6;     // col group 0..3
    const int l16  = lane & 15;
    const int lq   = lane >> 4;            // 0..3
    const int colbase = wv * 32;

    // preload W fragments (bf16)
    bf16x8 wf[4][2];
    #pragma unroll
    for (int kb = 0; kb < 4; ++kb)
        #pragma unroll
        for (int nb = 0; nb < 2; ++nb) {
            const int col = colbase + nb * 16 + l16;
            const int k0  = kb * 32 + lq * 8;
            bf16x8 t;
            #pragma unroll
            for (int j = 0; j < 8; ++j) t[j] = (__bf16)W[(k0 + j) * HH + col];
            wf[kb][nb] = t;
        }
    const float bs0 = bias[colbase + l16];
    const float bs1 = bias[colbase + 16 + l16];

    float w1f[32], b1f[32];
    if (AMODE == 1) {
        #pragma unroll
        for (int kb = 0; kb < 4; ++kb)
            #pragma unroll
            for (int j = 0; j < 8; ++j) {
                w1f[kb * 8 + j] = W1[kb * 32 + lq * 8 + j];
                b1f[kb * 8 + j] = b1[kb * 32 + lq * 8 + j];
            }
    }

    for (int tile = blockIdx.x; tile < ntiles; tile += gridDim.x) {
        const int r0 = tile * 16;

        bf16x8 af[4];
        if (AMODE == 0) {
            const float* arow = in + (size_t)(r0 + l16) * HH;
            #pragma unroll
            for (int kb = 0; kb < 4; ++kb) {
                const float4 lo = *(const float4*)(arow + kb * 32 + lq * 8);
                const float4 hi = *(const float4*)(arow + kb * 32 + lq * 8 + 4);
                bf16x8 t;
                t[0] = (__bf16)lo.x; t[1] = (__bf16)lo.y; t[2] = (__bf16)lo.z; t[3] = (__bf16)lo.w;
                t[4] = (__bf16)hi.x; t[5] = (__bf16)hi.y; t[6] = (__bf16)hi.z; t[7] = (__bf16)hi.w;
                af[kb] = t;
            }
        } else {
            const float s = in[r0 + l16];
            #pragma unroll
            for (int kb = 0; kb < 4; ++kb) {
                bf16x8 t;
                #pragma unroll
                for (int j = 0; j < 8; ++j)
                    t[j] = (__bf16)fmaxf(fmaf(s, w1f[kb * 8 + j], b1f[kb * 8 + j]), 0.f);
                af[kb] = t;
            }
        }

        if (SYNC) __syncthreads();   // in-place: all waves done reading tile rows

        f32x4 acc0 = (f32x4){bs0, bs0, bs0, bs0};
        f32x4 acc1 = (f32x4){bs1, bs1, bs1, bs1};
        #pragma unroll
        for (int kb = 0; kb < 4; ++kb) {
            acc0 = __builtin_amdgcn_mfma_f32_16x16x32_bf16(af[kb], wf[kb][0], acc0, 0, 0, 0);
            acc1 = __builtin_amdgcn_mfma_f32_16x16x32_bf16(af[kb], wf[kb][1], acc1, 0, 0, 0);
        }

        #pragma unroll
        for (int r = 0; r < 4; ++r) {
            const int row = r0 + lq * 4 + r;
            float v0 = acc0[r], v1 = acc1[r];
            if (ORELU) { v0 = fmaxf(v0, 0.f); v1 = fmaxf(v1, 0.f); }
            if (POOL) {
                const int g = batch[row];
                float* p = &pooled[(size_t)g * HH + colbase + l16];
                unsafeAtomicAdd(p, v0);
                unsafeAtomicAdd(p + 16, v1);
            } else {
                float* po = &out[(size_t)row * HH + colbase + l16];
                po[0] = v0; po[16] = v1;
            }
        }
    }
}

// ---------------------------------------------------------------- final FC
__global__ __launch_bounds__(128) void fc_k(const float* __restrict__ pooled,
                                            const float* __restrict__ Wfc,
                                            const float* __restrict__ bfc,
                                            float* __restrict__ out)
{
    __shared__ float p[HH];
    const int g = blockIdx.x, k = threadIdx.x;
    p[k] = pooled[g * HH + k];
    __syncthreads();
    float acc = bfc[k];
    #pragma unroll 8
    for (int j = 0; j < HH; ++j) acc = fmaf(p[j], Wfc[j * HH + k], acc);
    out[g * HH + k] = acc;
}

extern "C" void kernel_launch(void* const* d_in, const int* in_sizes, int n_in,
                              void* d_out, int out_size, void* d_ws, size_t ws_size,
                              hipStream_t stream)
{
    const float* x     = (const float*)d_in[0];
    const int*   ei    = (const int*)d_in[1];
    const int*   batch = (const int*)d_in[2];
    const float* W1_0 = (const float*)d_in[3];
    const float* b1_0 = (const float*)d_in[4];
    const float* W2_0 = (const float*)d_in[5];
    const float* b2_0 = (const float*)d_in[6];
    const float* W1_1 = (const float*)d_in[7];
    const float* b1_1 = (const float*)d_in[8];
    const float* W2_1 = (const float*)d_in[9];
    const float* b2_1 = (const float*)d_in[10];
    const float* W1_2 = (const float*)d_in[11];
    const float* b1_2 = (const float*)d_in[12];
    const float* W2_2 = (const float*)d_in[13];
    const float* b2_2 = (const float*)d_in[14];
    const float* Wfc  = (const float*)d_in[15];
    const float* bfc  = (const float*)d_in[16];

    const int N = in_sizes[0];          // 100000
    const int E = in_sizes[1] / 2;      // 640000
    const int* src = ei;
    const int* dst = ei + E;
    const int ntiles = N / 16;          // 6250

    float* z      = (float*)d_ws;                 // [N,128]
    float* h      = z + (size_t)N * HH;           // [N,128]
    float* z0     = h + (size_t)N * HH;           // [N]
    float* pooled = z0 + N;                       // [G,128]
    int* rowptr   = (int*)(pooled + GG * HH);     // [N+1]
    int* cnt      = rowptr + (N + 1);             // [N]
    int* eidx     = cnt + N;                      // [E]
    int* partial  = eidx + E;                     // [<=128]
    float* outp   = (float*)d_out;

    const int nbs = (N + SB - 1) / SB;            // scan blocks (98)

    // ---- CSR build (per call; cheap)
    zero_k<<<(N + 255) / 256, 256, 0, stream>>>(cnt, pooled, N);
    count_k<<<(E + 255) / 256, 256, 0, stream>>>(dst, cnt, E);
    scan1_k<<<nbs, SB, 0, stream>>>(cnt, rowptr, partial, N);
    scan2_k<<<1, 128, 0, stream>>>(partial, nbs);
    scan3_k<<<nbs, SB, 0, stream>>>(rowptr, partial, N, E);
    scatter_k<<<(E + 255) / 256, 256, 0, stream>>>(src, dst, rowptr, cnt, eidx, E);

    // ---- layer 0: z0 = x + pull-sum(x);  h <- relu(z0 (x) W1_0+b1_0) @ W2_0+b2_0
    agg0_k<<<(N + 255) / 256, 256, 0, stream>>>(x, rowptr, eidx, z0, N);
    gemm_mfma_k<1, 0, 0, 0><<<1024, 256, 0, stream>>>(
        z0, W1_0, b1_0, W2_0, b2_0, h, nullptr, nullptr, ntiles);

    // ---- layer 1
    aggw_k<<<2048, 256, 0, stream>>>(h, rowptr, eidx, z, N);
    gemm_mfma_k<0, 1, 0, 1><<<1024, 256, 0, stream>>>(
        z, nullptr, nullptr, W1_1, b1_1, z, nullptr, nullptr, ntiles);  // in-place
    gemm_mfma_k<0, 0, 0, 0><<<1024, 256, 0, stream>>>(
        z, nullptr, nullptr, W2_1, b2_1, h, nullptr, nullptr, ntiles);

    // ---- layer 2 (pool fused into second GEMM)
    aggw_k<<<2048, 256, 0, stream>>>(h, rowptr, eidx, z, N);
    gemm_mfma_k<0, 1, 0, 1><<<1024, 256, 0, stream>>>(
        z, nullptr, nullptr, W1_2, b1_2, z, nullptr, nullptr, ntiles);  // in-place
    gemm_mfma_k<0, 0, 1, 0><<<1024, 256, 0, stream>>>(
        z, nullptr, nullptr, W2_2, b2_2, nullptr, batch, pooled, ntiles);

    // ---- final FC
    fc_k<<<GG, HH, 0, stream>>>(pooled, Wfc, bfc, outp);
}

// Round 4
// 546.517 us; speedup vs baseline: 4.8163x; 1.2207x over previous
//
#include <hip/hip_runtime.h>

#define HH 128
#define GG 256
#define SB 1024

using f32x4  = __attribute__((ext_vector_type(4))) float;
using bf16x8 = __attribute__((ext_vector_type(8))) __bf16;

// ---------------------------------------------------------------- zero
__global__ __launch_bounds__(256) void zero_k(int* __restrict__ cnt,
                                              float* __restrict__ pooled, int n)
{
    int i = blockIdx.x * 256 + threadIdx.x;
    if (i < n) cnt[i] = 0;
    if (i < GG * HH) pooled[i] = 0.f;
}

// ---------------------------------------------------------------- CSR build
__global__ __launch_bounds__(256) void count_k(const int* __restrict__ dst,
                                               int* __restrict__ cnt, int ne)
{
    int e = blockIdx.x * 256 + threadIdx.x;
    if (e < ne) atomicAdd(&cnt[dst[e]], 1);
}

__global__ __launch_bounds__(SB) void scan1_k(const int* __restrict__ cnt,
                                              int* __restrict__ rowptr,
                                              int* __restrict__ partial, int n)
{
    __shared__ int s[SB];
    const int t = threadIdx.x, g = blockIdx.x * SB + t;
    const int v = (g < n) ? cnt[g] : 0;
    s[t] = v; __syncthreads();
    for (int off = 1; off < SB; off <<= 1) {
        int a = (t >= off) ? s[t - off] : 0; __syncthreads();
        s[t] += a; __syncthreads();
    }
    if (g < n) rowptr[g] = s[t] - v;             // exclusive within block
    if (t == SB - 1) partial[blockIdx.x] = s[t]; // block total
}

__global__ __launch_bounds__(128) void scan2_k(int* __restrict__ partial, int nb)
{
    __shared__ int s[128];
    const int t = threadIdx.x;
    const int v = (t < nb) ? partial[t] : 0;
    s[t] = v; __syncthreads();
    for (int off = 1; off < 128; off <<= 1) {
        int a = (t >= off) ? s[t - off] : 0; __syncthreads();
        s[t] += a; __syncthreads();
    }
    if (t < nb) partial[t] = s[t] - v;           // exclusive block offsets
}

__global__ __launch_bounds__(SB) void scan3_k(int* __restrict__ rowptr,
                                              const int* __restrict__ partial,
                                              int n, int ne)
{
    int g = blockIdx.x * SB + threadIdx.x;
    if (g < n) rowptr[g] += partial[blockIdx.x];
    if (g == n - 1) rowptr[n] = ne;
}

// countdown-scatter: consumes cnt (ends all-zero), fills eidx with src ids
__global__ __launch_bounds__(256) void scatter_k(const int* __restrict__ src,
                                                 const int* __restrict__ dst,
                                                 const int* __restrict__ rowptr,
                                                 int* __restrict__ cnt,
                                                 int* __restrict__ eidx, int ne)
{
    int e = blockIdx.x * 256 + threadIdx.x;
    if (e < ne) {
        const int d = dst[e];
        const int off = atomicSub(&cnt[d], 1) - 1;
        eidx[rowptr[d] + off] = src[e];
    }
}

// ---------------------------------------------------- pack W to frag order
// out[((nb*4+kb)*64 + lane)*8 + j] = bf16( W[(kb*32 + (lane>>4)*8 + j)*128 + nb*16 + (lane&15)] )
// B-frag layout for mfma_f32_16x16x32_bf16: col = lane&15, k = (lane>>4)*8 + j
__global__ __launch_bounds__(256) void packW_k(const float* __restrict__ W,
                                               __bf16* __restrict__ out)
{
    const int t = threadIdx.x;
    #pragma unroll
    for (int s = 0; s < 8; ++s) {
        const int slot = s * 256 + t;          // 0..2047
        const int frag = slot >> 6, lane = slot & 63;
        const int nb = frag >> 2, kb = frag & 3;
        const int col = nb * 16 + (lane & 15);
        const int k0  = kb * 32 + (lane >> 4) * 8;
        bf16x8 v;
        #pragma unroll
        for (int j = 0; j < 8; ++j) v[j] = (__bf16)W[(k0 + j) * HH + col];
        *(bf16x8*)&out[slot * 8] = v;
    }
}

// ------------------------------------------- layer0 scalar pull aggregation
__global__ __launch_bounds__(256) void agg0_k(const float* __restrict__ x,
                                              const int* __restrict__ rowptr,
                                              const int* __restrict__ eidx,
                                              float* __restrict__ z0, int n)
{
    int i = blockIdx.x * 256 + threadIdx.x;
    if (i < n) {
        float s = x[i];
        const int e = rowptr[i + 1];
        for (int j = rowptr[i]; j < e; ++j) s += x[eidx[j]];
        z0[i] = s;
    }
}

// ------------------------------------------- dense pull aggregation
// z[n][:] = h[n][:] + sum_{s in in(n)} h[s][:]   (wave per node, float2/lane)
__global__ __launch_bounds__(256) void aggw_k(const float* __restrict__ h,
                                              const int* __restrict__ rowptr,
                                              const int* __restrict__ eidx,
                                              float* __restrict__ z, int n)
{
    const int gw   = (blockIdx.x * 256 + threadIdx.x) >> 6;
    const int lane = threadIdx.x & 63;
    const int nw   = (gridDim.x * 256) >> 6;
    const float2* h2 = (const float2*)h;
    float2* z2 = (float2*)z;

    for (int node = gw; node < n; node += nw) {
        const int b = rowptr[node], e = rowptr[node + 1];
        float2 a0 = h2[(size_t)node * 64 + lane];
        float2 a1 = make_float2(0.f, 0.f);
        int j = b;
        for (; j + 1 < e; j += 2) {
            const int s0 = eidx[j], s1 = eidx[j + 1];
            const float2 v0 = h2[(size_t)s0 * 64 + lane];
            const float2 v1 = h2[(size_t)s1 * 64 + lane];
            a0.x += v0.x; a0.y += v0.y;
            a1.x += v1.x; a1.y += v1.y;
        }
        if (j < e) {
            const float2 v = h2[(size_t)eidx[j] * 64 + lane];
            a0.x += v.x; a0.y += v.y;
        }
        z2[(size_t)node * 64 + lane] = make_float2(a0.x + a1.x, a0.y + a1.y);
    }
}

// ------------------------------------------------------------- MFMA GEMM v3
// out[n][c] = epi(bias[c] + sum_j A[n][j] * W[j][c]);  W staged in LDS as
// pre-packed bf16 fragments (32KB), read with conflict-free ds_read_b128.
// Block = 4 waves x 32 rows = 128 rows; wave owns 32 rows x all 128 cols.
// AMODE 0: A = in (fp32 [M,128]);  AMODE 1: A[n][j] = relu(in[n]*W1[j]+b1[j])
// In-place (out==in) is safe: each wave reads/writes only its own rows.
template<int AMODE, int ORELU, int POOL>
__global__ __launch_bounds__(256) void gemm_v3_k(
    const float* in,
    const float* __restrict__ W1, const float* __restrict__ b1,
    const __bf16* __restrict__ Wp, const float* __restrict__ bias,
    float* out,
    const int* __restrict__ batch, float* __restrict__ pooled,
    int n)
{
    __shared__ __bf16 Wl[32 * 64 * 8];   // 32 KB: [frag][lane][8]
    __shared__ float w1l[HH], b1l[HH];

    const int t = threadIdx.x;
    #pragma unroll
    for (int i = 0; i < 8; ++i)
        *(int4*)&Wl[(i * 256 + t) * 8] = *(const int4*)&Wp[(i * 256 + t) * 8];
    if (AMODE == 1) {
        if (t < HH) w1l[t] = W1[t];
        else if (t < 2 * HH) b1l[t - HH] = b1[t - HH];
    }
    __syncthreads();

    const int lane = t & 63, wv = t >> 6;
    const int l16 = lane & 15, lq = lane >> 4;
    const int r0 = blockIdx.x * 128 + wv * 32;     // this wave's rows
    if (r0 >= n) return;
    const bool hi_ok = (r0 + 16) < n;              // n % 16 == 0

    // ---- A fragments (A-layout: row = lane&15, k = (lane>>4)*8 + j)
    bf16x8 af0[4], af1[4];
    if (AMODE == 0) {
        const float* a0 = in + (size_t)(r0 + l16) * HH + lq * 8;
        #pragma unroll
        for (int kb = 0; kb < 4; ++kb) {
            const float4 lo = *(const float4*)(a0 + kb * 32);
            const float4 hi = *(const float4*)(a0 + kb * 32 + 4);
            bf16x8 v;
            v[0] = (__bf16)lo.x; v[1] = (__bf16)lo.y; v[2] = (__bf16)lo.z; v[3] = (__bf16)lo.w;
            v[4] = (__bf16)hi.x; v[5] = (__bf16)hi.y; v[6] = (__bf16)hi.z; v[7] = (__bf16)hi.w;
            af0[kb] = v;
        }
        if (hi_ok) {
            const float* a1 = a0 + 16 * HH;
            #pragma unroll
            for (int kb = 0; kb < 4; ++kb) {
                const float4 lo = *(const float4*)(a1 + kb * 32);
                const float4 hi = *(const float4*)(a1 + kb * 32 + 4);
                bf16x8 v;
                v[0] = (__bf16)lo.x; v[1] = (__bf16)lo.y; v[2] = (__bf16)lo.z; v[3] = (__bf16)lo.w;
                v[4] = (__bf16)hi.x; v[5] = (__bf16)hi.y; v[6] = (__bf16)hi.z; v[7] = (__bf16)hi.w;
                af1[kb] = v;
            }
        } else {
            #pragma unroll
            for (int kb = 0; kb < 4; ++kb) af1[kb] = (bf16x8){};
        }
    } else {
        const float s0 = in[r0 + l16];
        const float s1 = hi_ok ? in[r0 + 16 + l16] : 0.f;
        #pragma unroll
        for (int kb = 0; kb < 4; ++kb) {
            const float4 wA = *(const float4*)&w1l[kb * 32 + lq * 8];
            const float4 wB = *(const float4*)&w1l[kb * 32 + lq * 8 + 4];
            const float4 bA = *(const float4*)&b1l[kb * 32 + lq * 8];
            const float4 bB = *(const float4*)&b1l[kb * 32 + lq * 8 + 4];
            bf16x8 v0, v1;
            v0[0] = (__bf16)fmaxf(fmaf(s0, wA.x, bA.x), 0.f);
            v0[1] = (__bf16)fmaxf(fmaf(s0, wA.y, bA.y), 0.f);
            v0[2] = (__bf16)fmaxf(fmaf(s0, wA.z, bA.z), 0.f);
            v0[3] = (__bf16)fmaxf(fmaf(s0, wA.w, bA.w), 0.f);
            v0[4] = (__bf16)fmaxf(fmaf(s0, wB.x, bB.x), 0.f);
            v0[5] = (__bf16)fmaxf(fmaf(s0, wB.y, bB.y), 0.f);
            v0[6] = (__bf16)fmaxf(fmaf(s0, wB.z, bB.z), 0.f);
            v0[7] = (__bf16)fmaxf(fmaf(s0, wB.w, bB.w), 0.f);
            v1[0] = (__bf16)fmaxf(fmaf(s1, wA.x, bA.x), 0.f);
            v1[1] = (__bf16)fmaxf(fmaf(s1, wA.y, bA.y), 0.f);
            v1[2] = (__bf16)fmaxf(fmaf(s1, wA.z, bA.z), 0.f);
            v1[3] = (__bf16)fmaxf(fmaf(s1, wA.w, bA.w), 0.f);
            v1[4] = (__bf16)fmaxf(fmaf(s1, wB.x, bB.x), 0.f);
            v1[5] = (__bf16)fmaxf(fmaf(s1, wB.y, bB.y), 0.f);
            v1[6] = (__bf16)fmaxf(fmaf(s1, wB.z, bB.z), 0.f);
            v1[7] = (__bf16)fmaxf(fmaf(s1, wB.w, bB.w), 0.f);
            af0[kb] = v0; af1[kb] = v1;
        }
    }

    // ---- accumulate: acc[half][nb], B-frag from LDS reused across halves
    f32x4 acc0[8], acc1[8];
    #pragma unroll
    for (int nb = 0; nb < 8; ++nb) {
        const float bs = bias[nb * 16 + l16];
        acc0[nb] = (f32x4){bs, bs, bs, bs};
        acc1[nb] = acc0[nb];
    }
    #pragma unroll
    for (int nb = 0; nb < 8; ++nb) {
        #pragma unroll
        for (int kb = 0; kb < 4; ++kb) {
            const bf16x8 bf = *(const bf16x8*)&Wl[((nb * 4 + kb) * 64 + lane) * 8];
            acc0[nb] = __builtin_amdgcn_mfma_f32_16x16x32_bf16(af0[kb], bf, acc0[nb], 0, 0, 0);
            acc1[nb] = __builtin_amdgcn_mfma_f32_16x16x32_bf16(af1[kb], bf, acc1[nb], 0, 0, 0);
        }
    }

    // ---- epilogue (D-layout: col = lane&15, row = (lane>>4)*4 + r)
    #pragma unroll
    for (int nb = 0; nb < 8; ++nb) {
        #pragma unroll
        for (int r = 0; r < 4; ++r) {
            const int row = r0 + lq * 4 + r;
            float v = acc0[nb][r];
            if (ORELU) v = fmaxf(v, 0.f);
            if (POOL) {
                unsafeAtomicAdd(&pooled[(size_t)batch[row] * HH + nb * 16 + l16], v);
            } else {
                out[(size_t)row * HH + nb * 16 + l16] = v;
            }
        }
    }
    if (hi_ok) {
        #pragma unroll
        for (int nb = 0; nb < 8; ++nb) {
            #pragma unroll
            for (int r = 0; r < 4; ++r) {
                const int row = r0 + 16 + lq * 4 + r;
                float v = acc1[nb][r];
                if (ORELU) v = fmaxf(v, 0.f);
                if (POOL) {
                    unsafeAtomicAdd(&pooled[(size_t)batch[row] * HH + nb * 16 + l16], v);
                } else {
                    out[(size_t)row * HH + nb * 16 + l16] = v;
                }
            }
        }
    }
}

// ---------------------------------------------------------------- final FC
__global__ __launch_bounds__(128) void fc_k(const float* __restrict__ pooled,
                                            const float* __restrict__ Wfc,
                                            const float* __restrict__ bfc,
                                            float* __restrict__ out)
{
    __shared__ float p[HH];
    const int g = blockIdx.x, k = threadIdx.x;
    p[k] = pooled[g * HH + k];
    __syncthreads();
    float acc = bfc[k];
    #pragma unroll 8
    for (int j = 0; j < HH; ++j) acc = fmaf(p[j], Wfc[j * HH + k], acc);
    out[g * HH + k] = acc;
}

extern "C" void kernel_launch(void* const* d_in, const int* in_sizes, int n_in,
                              void* d_out, int out_size, void* d_ws, size_t ws_size,
                              hipStream_t stream)
{
    const float* x     = (const float*)d_in[0];
    const int*   ei    = (const int*)d_in[1];
    const int*   batch = (const int*)d_in[2];
    const float* W1_0 = (const float*)d_in[3];
    const float* b1_0 = (const float*)d_in[4];
    const float* W2_0 = (const float*)d_in[5];
    const float* b2_0 = (const float*)d_in[6];
    const float* W1_1 = (const float*)d_in[7];
    const float* b1_1 = (const float*)d_in[8];
    const float* W2_1 = (const float*)d_in[9];
    const float* b2_1 = (const float*)d_in[10];
    const float* W1_2 = (const float*)d_in[11];
    const float* b1_2 = (const float*)d_in[12];
    const float* W2_2 = (const float*)d_in[13];
    const float* b2_2 = (const float*)d_in[14];
    const float* Wfc  = (const float*)d_in[15];
    const float* bfc  = (const float*)d_in[16];

    const int N = in_sizes[0];          // 100000
    const int E = in_sizes[1] / 2;      // 640000
    const int* src = ei;
    const int* dst = ei + E;

    float* z      = (float*)d_ws;                 // [N,128]
    float* h      = z + (size_t)N * HH;           // [N,128]
    float* z0     = h + (size_t)N * HH;           // [N]
    float* pooled = z0 + N;                       // [G,128]
    int* rowptr   = (int*)(pooled + GG * HH);     // [N+1]
    int* cnt      = rowptr + (N + 1);             // [N]
    int* eidx     = cnt + N;                      // [E]
    int* partial  = eidx + E;                     // [<=128]
    __bf16* Wp    = (__bf16*)(partial + 128);     // 5 x 128x128 bf16 packed
    float* outp   = (float*)d_out;

    const int nbs = (N + SB - 1) / SB;            // scan blocks (98)
    const int gblk = (N + 127) / 128;             // gemm blocks (782)

    // ---- CSR build (per call; cheap)
    zero_k<<<(N + 255) / 256, 256, 0, stream>>>(cnt, pooled, N);
    count_k<<<(E + 255) / 256, 256, 0, stream>>>(dst, cnt, E);
    scan1_k<<<nbs, SB, 0, stream>>>(cnt, rowptr, partial, N);
    scan2_k<<<1, 128, 0, stream>>>(partial, nbs);
    scan3_k<<<nbs, SB, 0, stream>>>(rowptr, partial, N, E);
    scatter_k<<<(E + 255) / 256, 256, 0, stream>>>(src, dst, rowptr, cnt, eidx, E);

    // ---- pack weights to bf16 fragment order
    packW_k<<<1, 256, 0, stream>>>(W2_0, Wp);
    packW_k<<<1, 256, 0, stream>>>(W1_1, Wp + 16384);
    packW_k<<<1, 256, 0, stream>>>(W2_1, Wp + 2 * 16384);
    packW_k<<<1, 256, 0, stream>>>(W1_2, Wp + 3 * 16384);
    packW_k<<<1, 256, 0, stream>>>(W2_2, Wp + 4 * 16384);

    // ---- layer 0: z0 = x + pull-sum(x);  h <- relu(z0 (x) W1_0+b1_0) @ W2_0+b2_0
    agg0_k<<<(N + 255) / 256, 256, 0, stream>>>(x, rowptr, eidx, z0, N);
    gemm_v3_k<1, 0, 0><<<gblk, 256, 0, stream>>>(
        z0, W1_0, b1_0, Wp, b2_0, h, nullptr, nullptr, N);

    // ---- layer 1
    aggw_k<<<2048, 256, 0, stream>>>(h, rowptr, eidx, z, N);
    gemm_v3_k<0, 1, 0><<<gblk, 256, 0, stream>>>(
        z, nullptr, nullptr, Wp + 16384, b1_1, z, nullptr, nullptr, N);   // in-place
    gemm_v3_k<0, 0, 0><<<gblk, 256, 0, stream>>>(
        z, nullptr, nullptr, Wp + 2 * 16384, b2_1, h, nullptr, nullptr, N);

    // ---- layer 2 (pool fused into second GEMM)
    aggw_k<<<2048, 256, 0, stream>>>(h, rowptr, eidx, z, N);
    gemm_v3_k<0, 1, 0><<<gblk, 256, 0, stream>>>(
        z, nullptr, nullptr, Wp + 3 * 16384, b1_2, z, nullptr, nullptr, N);  // in-place
    gemm_v3_k<0, 0, 1><<<gblk, 256, 0, stream>>>(
        z, nullptr, nullptr, Wp + 4 * 16384, b2_2, nullptr, batch, pooled, N);

    // ---- final FC
    fc_k<<<GG, HH, 0, stream>>>(pooled, Wfc, bfc, outp);
}

// Round 5
// 303.970 us; speedup vs baseline: 8.6593x; 1.7979x over previous
//
#include <hip/hip_runtime.h>

#define HH 128
#define GG 256
#define SB 1024

using f32x4  = __attribute__((ext_vector_type(4))) float;
using bf16x4 = __attribute__((ext_vector_type(4))) __bf16;
using bf16x8 = __attribute__((ext_vector_type(8))) __bf16;

static __device__ __forceinline__ float bf2f(unsigned int u) {
    unsigned int x = u << 16;
    return __builtin_bit_cast(float, x);
}
static __device__ __forceinline__ unsigned short f2bf(float f) {
    __bf16 b = (__bf16)f;
    return __builtin_bit_cast(unsigned short, b);
}

// ---------------------------------------------------------------- zero
__global__ __launch_bounds__(256) void zero_k(int* __restrict__ cnt, int n)
{
    int i = blockIdx.x * 256 + threadIdx.x;
    if (i < n) cnt[i] = 0;
}

// ---------------------------------------------------------------- CSR build
__global__ __launch_bounds__(256) void count_k(const int* __restrict__ dst,
                                               int* __restrict__ cnt, int ne)
{
    int e = blockIdx.x * 256 + threadIdx.x;
    if (e < ne) atomicAdd(&cnt[dst[e]], 1);
}

__global__ __launch_bounds__(SB) void scan1_k(const int* __restrict__ cnt,
                                              int* __restrict__ rowptr,
                                              int* __restrict__ partial, int n)
{
    __shared__ int s[SB];
    const int t = threadIdx.x, g = blockIdx.x * SB + t;
    const int v = (g < n) ? cnt[g] : 0;
    s[t] = v; __syncthreads();
    for (int off = 1; off < SB; off <<= 1) {
        int a = (t >= off) ? s[t - off] : 0; __syncthreads();
        s[t] += a; __syncthreads();
    }
    if (g < n) rowptr[g] = s[t] - v;             // exclusive within block
    if (t == SB - 1) partial[blockIdx.x] = s[t]; // block total
}

__global__ __launch_bounds__(128) void scan2_k(int* __restrict__ partial, int nb)
{
    __shared__ int s[128];
    const int t = threadIdx.x;
    const int v = (t < nb) ? partial[t] : 0;
    s[t] = v; __syncthreads();
    for (int off = 1; off < 128; off <<= 1) {
        int a = (t >= off) ? s[t - off] : 0; __syncthreads();
        s[t] += a; __syncthreads();
    }
    if (t < nb) partial[t] = s[t] - v;           // exclusive block offsets
}

__global__ __launch_bounds__(SB) void scan3_k(int* __restrict__ rowptr,
                                              const int* __restrict__ partial,
                                              int n, int ne)
{
    int g = blockIdx.x * SB + threadIdx.x;
    if (g < n) rowptr[g] += partial[blockIdx.x];
    if (g == n - 1) rowptr[n] = ne;
}

// countdown-scatter: consumes cnt (ends all-zero), fills eidx with src ids
__global__ __launch_bounds__(256) void scatter_k(const int* __restrict__ src,
                                                 const int* __restrict__ dst,
                                                 const int* __restrict__ rowptr,
                                                 int* __restrict__ cnt,
                                                 int* __restrict__ eidx, int ne)
{
    int e = blockIdx.x * 256 + threadIdx.x;
    if (e < ne) {
        const int d = dst[e];
        const int off = atomicSub(&cnt[d], 1) - 1;
        eidx[rowptr[d] + off] = src[e];
    }
}

// ------------------------------------------- graph boundaries (batch sorted)
__global__ __launch_bounds__(256) void bound_k(const int* __restrict__ batch,
                                               int* __restrict__ bound, int n)
{
    const int g = threadIdx.x;   // 0..255
    int lo = 0, hi = n;
    while (lo < hi) { int m = (lo + hi) >> 1; if (batch[m] < g) lo = m + 1; else hi = m; }
    bound[g] = lo;
    if (g == 0) bound[GG] = n;
}

// ---------------------------------------------------- pack W to frag order
// slot = frag*64 + lane; frag = mb*4 + kb
// out[slot*8 + j] = bf16( W[(kb*32 + (lane>>4)*8 + j)*128 + mb*16 + (lane&15)] )
// This layout serves as A-frags of W^T (and equally B-frags of W).
__global__ __launch_bounds__(256) void packW_k(const float* __restrict__ W,
                                               __bf16* __restrict__ out)
{
    const int slot = blockIdx.x * 256 + threadIdx.x;   // 0..2047
    const int frag = slot >> 6, lane = slot & 63;
    const int mb = frag >> 2, kb = frag & 3;
    const int col = mb * 16 + (lane & 15);
    const int k0  = kb * 32 + (lane >> 4) * 8;
    bf16x8 v;
    #pragma unroll
    for (int j = 0; j < 8; ++j) v[j] = (__bf16)W[(k0 + j) * HH + col];
    *(bf16x8*)&out[slot * 8] = v;
}

// ------------------------------------------- layer0 scalar pull aggregation
__global__ __launch_bounds__(256) void agg0_k(const float* __restrict__ x,
                                              const int* __restrict__ rowptr,
                                              const int* __restrict__ eidx,
                                              float* __restrict__ z0, int n)
{
    int i = blockIdx.x * 256 + threadIdx.x;
    if (i < n) {
        float s = x[i];
        const int e = rowptr[i + 1];
        for (int j = rowptr[i]; j < e; ++j) s += x[eidx[j]];
        z0[i] = s;
    }
}

// ------------------------------------------- dense pull aggregation (bf16)
// z[n][:] = h[n][:] + sum_{s in in(n)} h[s][:]; wave per node, 2 cols/lane
static __device__ __forceinline__ void agg_body(
    const unsigned short* __restrict__ h, const int* __restrict__ rowptr,
    const int* __restrict__ eidx, unsigned short* __restrict__ z, int n)
{
    const int gw   = (blockIdx.x * 256 + threadIdx.x) >> 6;
    const int lane = threadIdx.x & 63;
    const int nw   = (gridDim.x * 256) >> 6;
    const unsigned int* h4 = (const unsigned int*)h;   // 2 bf16 per u32
    unsigned int* z4 = (unsigned int*)z;

    for (int node = gw; node < n; node += nw) {
        const int b = rowptr[node], e = rowptr[node + 1];
        const unsigned int su = h4[(size_t)node * 64 + lane];
        float a0 = bf2f(su & 0xffff), a1 = bf2f(su >> 16);
        float b0 = 0.f, b1 = 0.f, c0 = 0.f, c1 = 0.f, d0 = 0.f, d1 = 0.f;
        int j = b;
        for (; j + 3 < e; j += 4) {
            const unsigned int v0 = h4[(size_t)eidx[j]     * 64 + lane];
            const unsigned int v1 = h4[(size_t)eidx[j + 1] * 64 + lane];
            const unsigned int v2 = h4[(size_t)eidx[j + 2] * 64 + lane];
            const unsigned int v3 = h4[(size_t)eidx[j + 3] * 64 + lane];
            a0 += bf2f(v0 & 0xffff); a1 += bf2f(v0 >> 16);
            b0 += bf2f(v1 & 0xffff); b1 += bf2f(v1 >> 16);
            c0 += bf2f(v2 & 0xffff); c1 += bf2f(v2 >> 16);
            d0 += bf2f(v3 & 0xffff); d1 += bf2f(v3 >> 16);
        }
        for (; j < e; ++j) {
            const unsigned int v = h4[(size_t)eidx[j] * 64 + lane];
            a0 += bf2f(v & 0xffff); a1 += bf2f(v >> 16);
        }
        const float s0 = (a0 + b0) + (c0 + d0);
        const float s1 = (a1 + b1) + (c1 + d1);
        z4[(size_t)node * 64 + lane] = (unsigned int)f2bf(s0) | ((unsigned int)f2bf(s1) << 16);
    }
}
__global__ __launch_bounds__(256) void agg1_k(const unsigned short* h, const int* rowptr,
                                              const int* eidx, unsigned short* z, int n)
{ agg_body(h, rowptr, eidx, z, n); }
__global__ __launch_bounds__(256) void agg2_k(const unsigned short* h, const int* rowptr,
                                              const int* eidx, unsigned short* z, int n)
{ agg_body(h, rowptr, eidx, z, n); }

// ------------------------------------------------------------- fused MLP
// h = relu(z @ W1 + b1) @ W2 + b2, computed transposed:
//   t^T = W1^T @ z^T  (MFMA, A = packed W1^T frags, B = z rows as-loaded)
//   bounce t through wave-local swizzled LDS tile (bf16)
//   h^T = W2^T @ t^T  -> lane holds 4 consecutive h-cols of one node.
// Block: 4 waves x 32 nodes = 128 nodes. L0: t built directly from scalar z0.
template<int L0>
static __device__ __forceinline__ void mlp_body(
    const void* __restrict__ zin,               // L0: float[N] ; else ushort[N][128]
    const __bf16* __restrict__ Wp1, const float* __restrict__ b1,
    const __bf16* __restrict__ Wp2, const float* __restrict__ b2,
    const float* __restrict__ W1raw,            // L0 only: [128]
    unsigned short* __restrict__ hout, int n)
{
    __shared__ __bf16 Wl[16384];                // 32 KB (W1T then W2T; L0: W2T)
    __shared__ unsigned short tt[4][4096];      // 8 KB per-wave t-tile
    __shared__ float b1l[HH], b2l[HH], w1l[HH];

    const int t    = threadIdx.x;
    const int lane = t & 63, wv = t >> 6;
    const int l16  = lane & 15, lq = lane >> 4;
    const int r0    = blockIdx.x * 128 + wv * 32;
    const int nodeA = r0 + l16, nodeB = r0 + 16 + l16;
    const int rowA  = min(nodeA, n - 1), rowB = min(nodeB, n - 1);
    const int swz   = (l16 & 7) << 4;           // (node&7)<<4 ; node≡l16 (mod 8)

    {   // stage first W + biases
        const __bf16* Wfirst = L0 ? Wp2 : Wp1;
        #pragma unroll
        for (int i = 0; i < 8; ++i)
            *(int4*)&Wl[(i * 256 + t) * 8] = *(const int4*)&Wfirst[(i * 256 + t) * 8];
        if (t < HH) {
            b2l[t] = b2[t];
            b1l[t] = b1[t];
            if (L0) w1l[t] = W1raw[t];
        }
    }
    __syncthreads();

    unsigned short* tl = tt[wv];

    // ---- produce t-tile (32 nodes x 128 tcols, bf16, swizzled)
    if (L0) {
        const float* z0 = (const float*)zin;
        const float sA = z0[rowA], sB = z0[rowB];
        #pragma unroll
        for (int mt = 0; mt < 8; ++mt) {
            const f32x4 w  = *(const f32x4*)&w1l[mt * 16 + lq * 4];
            const f32x4 bb = *(const f32x4*)&b1l[mt * 16 + lq * 4];
            bf16x4 pa, pb;
            #pragma unroll
            for (int r = 0; r < 4; ++r) {
                pa[r] = (__bf16)fmaxf(fmaf(sA, w[r], bb[r]), 0.f);
                pb[r] = (__bf16)fmaxf(fmaf(sB, w[r], bb[r]), 0.f);
            }
            *(bf16x4*)((char*)tl + ((l16 * 256 + mt * 32 + lq * 8) ^ swz)) = pa;
            *(bf16x4*)((char*)tl + (((16 + l16) * 256 + mt * 32 + lq * 8) ^ swz)) = pb;
        }
    } else {
        const unsigned short* z = (const unsigned short*)zin;
        bf16x8 zfA[4], zfB[4];
        #pragma unroll
        for (int kb = 0; kb < 4; ++kb) {
            zfA[kb] = *(const bf16x8*)&z[(size_t)rowA * HH + kb * 32 + lq * 8];
            zfB[kb] = *(const bf16x8*)&z[(size_t)rowB * HH + kb * 32 + lq * 8];
        }
        f32x4 a1A[8], a1B[8];
        #pragma unroll
        for (int mt = 0; mt < 8; ++mt) {
            const f32x4 bb = *(const f32x4*)&b1l[mt * 16 + lq * 4];
            a1A[mt] = bb; a1B[mt] = bb;
        }
        #pragma unroll
        for (int mt = 0; mt < 8; ++mt)
            #pragma unroll
            for (int kb = 0; kb < 4; ++kb) {
                const bf16x8 wf = *(const bf16x8*)&Wl[((mt * 4 + kb) * 64 + lane) * 8];
                a1A[mt] = __builtin_amdgcn_mfma_f32_16x16x32_bf16(wf, zfA[kb], a1A[mt], 0, 0, 0);
                a1B[mt] = __builtin_amdgcn_mfma_f32_16x16x32_bf16(wf, zfB[kb], a1B[mt], 0, 0, 0);
            }
        #pragma unroll
        for (int mt = 0; mt < 8; ++mt) {
            bf16x4 pa, pb;
            #pragma unroll
            for (int r = 0; r < 4; ++r) {
                pa[r] = (__bf16)fmaxf(a1A[mt][r], 0.f);
                pb[r] = (__bf16)fmaxf(a1B[mt][r], 0.f);
            }
            *(bf16x4*)((char*)tl + ((l16 * 256 + mt * 32 + lq * 8) ^ swz)) = pa;
            *(bf16x4*)((char*)tl + (((16 + l16) * 256 + mt * 32 + lq * 8) ^ swz)) = pb;
        }
    }

    if (!L0) {                 // restage W2 (all waves done reading W1)
        __syncthreads();
        #pragma unroll
        for (int i = 0; i < 8; ++i)
            *(int4*)&Wl[(i * 256 + t) * 8] = *(const int4*)&Wp2[(i * 256 + t) * 8];
        __syncthreads();
    }

    // ---- MFMA2: h^T = W2^T @ t^T
    bf16x8 tfA[4], tfB[4];
    #pragma unroll
    for (int kb = 0; kb < 4; ++kb) {
        tfA[kb] = *(const bf16x8*)((char*)tl + ((l16 * 256 + kb * 64 + lq * 16) ^ swz));
        tfB[kb] = *(const bf16x8*)((char*)tl + (((16 + l16) * 256 + kb * 64 + lq * 16) ^ swz));
    }
    f32x4 a2A[8], a2B[8];
    #pragma unroll
    for (int mb = 0; mb < 8; ++mb) {
        const f32x4 bb = *(const f32x4*)&b2l[mb * 16 + lq * 4];
        a2A[mb] = bb; a2B[mb] = bb;
    }
    #pragma unroll
    for (int mb = 0; mb < 8; ++mb)
        #pragma unroll
        for (int kb = 0; kb < 4; ++kb) {
            const bf16x8 wf = *(const bf16x8*)&Wl[((mb * 4 + kb) * 64 + lane) * 8];
            a2A[mb] = __builtin_amdgcn_mfma_f32_16x16x32_bf16(wf, tfA[kb], a2A[mb], 0, 0, 0);
            a2B[mb] = __builtin_amdgcn_mfma_f32_16x16x32_bf16(wf, tfB[kb], a2B[mb], 0, 0, 0);
        }

    // ---- store h (bf16): lane holds cols mb*16+lq*4..+3 of its node
    if (nodeA < n) {
        #pragma unroll
        for (int mb = 0; mb < 8; ++mb) {
            bf16x4 p;
            #pragma unroll
            for (int r = 0; r < 4; ++r) p[r] = (__bf16)a2A[mb][r];
            *(bf16x4*)&hout[(size_t)nodeA * HH + mb * 16 + lq * 4] = p;
        }
    }
    if (nodeB < n) {
        #pragma unroll
        for (int mb = 0; mb < 8; ++mb) {
            bf16x4 p;
            #pragma unroll
            for (int r = 0; r < 4; ++r) p[r] = (__bf16)a2B[mb][r];
            *(bf16x4*)&hout[(size_t)nodeB * HH + mb * 16 + lq * 4] = p;
        }
    }
}

__global__ __launch_bounds__(256) void l0_k(const float* z0, const float* W1, const float* b1,
                                            const __bf16* Wp2, const float* b2,
                                            unsigned short* h, int n)
{ mlp_body<1>(z0, nullptr, b1, Wp2, b2, W1, h, n); }

__global__ __launch_bounds__(256) void mlp1_k(const unsigned short* z,
                                              const __bf16* Wp1, const float* b1,
                                              const __bf16* Wp2, const float* b2,
                                              unsigned short* h, int n)
{ mlp_body<0>(z, Wp1, b1, Wp2, b2, nullptr, h, n); }

__global__ __launch_bounds__(256) void mlp2_k(const unsigned short* z,
                                              const __bf16* Wp1, const float* b1,
                                              const __bf16* Wp2, const float* b2,
                                              unsigned short* h, int n)
{ mlp_body<0>(z, Wp1, b1, Wp2, b2, nullptr, h, n); }

// ------------------------------------------------------- segment pooling
__global__ __launch_bounds__(128) void pool_k(const unsigned short* __restrict__ h,
                                              const int* __restrict__ bound,
                                              float* __restrict__ pooled)
{
    const int g = blockIdx.x, c = threadIdx.x;
    const int rb = bound[g], re = bound[g + 1];
    float s0 = 0.f, s1 = 0.f;
    int r = rb;
    for (; r + 1 < re; r += 2) {
        s0 += bf2f((unsigned int)h[(size_t)r * HH + c]);
        s1 += bf2f((unsigned int)h[(size_t)(r + 1) * HH + c]);
    }
    if (r < re) s0 += bf2f((unsigned int)h[(size_t)r * HH + c]);
    pooled[g * HH + c] = s0 + s1;
}

// ---------------------------------------------------------------- final FC
__global__ __launch_bounds__(128) void fc_k(const float* __restrict__ pooled,
                                            const float* __restrict__ Wfc,
                                            const float* __restrict__ bfc,
                                            float* __restrict__ out)
{
    __shared__ float p[HH];
    const int g = blockIdx.x, k = threadIdx.x;
    p[k] = pooled[g * HH + k];
    __syncthreads();
    float acc = bfc[k];
    #pragma unroll 8
    for (int j = 0; j < HH; ++j) acc = fmaf(p[j], Wfc[j * HH + k], acc);
    out[g * HH + k] = acc;
}

extern "C" void kernel_launch(void* const* d_in, const int* in_sizes, int n_in,
                              void* d_out, int out_size, void* d_ws, size_t ws_size,
                              hipStream_t stream)
{
    const float* x     = (const float*)d_in[0];
    const int*   ei    = (const int*)d_in[1];
    const int*   batch = (const int*)d_in[2];
    const float* W1_0 = (const float*)d_in[3];
    const float* b1_0 = (const float*)d_in[4];
    const float* W2_0 = (const float*)d_in[5];
    const float* b2_0 = (const float*)d_in[6];
    const float* W1_1 = (const float*)d_in[7];
    const float* b1_1 = (const float*)d_in[8];
    const float* W2_1 = (const float*)d_in[9];
    const float* b2_1 = (const float*)d_in[10];
    const float* W1_2 = (const float*)d_in[11];
    const float* b1_2 = (const float*)d_in[12];
    const float* W2_2 = (const float*)d_in[13];
    const float* b2_2 = (const float*)d_in[14];
    const float* Wfc  = (const float*)d_in[15];
    const float* bfc  = (const float*)d_in[16];

    const int N = in_sizes[0];          // 100000
    const int E = in_sizes[1] / 2;      // 640000
    const int* src = ei;
    const int* dst = ei + E;

    // ---- workspace carve (256B aligned sections)
    char* p = (char*)d_ws;
    #define CARVE(ty, name, count) ty* name = (ty*)p; p += (((size_t)(count) * sizeof(ty)) + 255) & ~(size_t)255;
    CARVE(unsigned short, z,      (size_t)N * HH)
    CARVE(unsigned short, h,      (size_t)N * HH)
    CARVE(float,          z0,     N)
    CARVE(float,          pooled, GG * HH)
    CARVE(int,            rowptr, N + 1)
    CARVE(int,            cnt,    N)
    CARVE(int,            eidx,   E)
    CARVE(int,            partial,128)
    CARVE(int,            bound,  GG + 1)
    CARVE(__bf16,         Wp,     5 * 16384)
    #undef CARVE
    float* outp = (float*)d_out;

    const int nbs  = (N + SB - 1) / SB;   // scan blocks (98)
    const int gblk = (N + 127) / 128;     // mlp blocks (782)

    // ---- CSR build + graph bounds
    zero_k<<<(N + 255) / 256, 256, 0, stream>>>(cnt, N);
    count_k<<<(E + 255) / 256, 256, 0, stream>>>(dst, cnt, E);
    scan1_k<<<nbs, SB, 0, stream>>>(cnt, rowptr, partial, N);
    scan2_k<<<1, 128, 0, stream>>>(partial, nbs);
    scan3_k<<<nbs, SB, 0, stream>>>(rowptr, partial, N, E);
    scatter_k<<<(E + 255) / 256, 256, 0, stream>>>(src, dst, rowptr, cnt, eidx, E);
    bound_k<<<1, 256, 0, stream>>>(batch, bound, N);

    // ---- pack weights (frag order, bf16)
    packW_k<<<8, 256, 0, stream>>>(W2_0, Wp);
    packW_k<<<8, 256, 0, stream>>>(W1_1, Wp + 16384);
    packW_k<<<8, 256, 0, stream>>>(W2_1, Wp + 2 * 16384);
    packW_k<<<8, 256, 0, stream>>>(W1_2, Wp + 3 * 16384);
    packW_k<<<8, 256, 0, stream>>>(W2_2, Wp + 4 * 16384);

    // ---- layer 0
    agg0_k<<<(N + 255) / 256, 256, 0, stream>>>(x, rowptr, eidx, z0, N);
    l0_k<<<gblk, 256, 0, stream>>>(z0, W1_0, b1_0, Wp, b2_0, h, N);

    // ---- layer 1
    agg1_k<<<2048, 256, 0, stream>>>(h, rowptr, eidx, z, N);
    mlp1_k<<<gblk, 256, 0, stream>>>(z, Wp + 16384, b1_1, Wp + 2 * 16384, b2_1, h, N);

    // ---- layer 2
    agg2_k<<<2048, 256, 0, stream>>>(h, rowptr, eidx, z, N);
    mlp2_k<<<gblk, 256, 0, stream>>>(z, Wp + 3 * 16384, b1_2, Wp + 4 * 16384, b2_2, h, N);

    // ---- pool + FC
    pool_k<<<GG, 128, 0, stream>>>(h, bound, pooled);
    fc_k<<<GG, HH, 0, stream>>>(pooled, Wfc, bfc, outp);
}

// Round 6
// 255.654 us; speedup vs baseline: 10.2959x; 1.1890x over previous
//
#include <hip/hip_runtime.h>

#define HH 128
#define GG 256
#define SB 1024
#define PSPLIT 16

using f32x4  = __attribute__((ext_vector_type(4))) float;
using bf16x4 = __attribute__((ext_vector_type(4))) __bf16;
using bf16x8 = __attribute__((ext_vector_type(8))) __bf16;

static __device__ __forceinline__ float bf2f(unsigned int u) {
    unsigned int x = u << 16;
    return __builtin_bit_cast(float, x);
}
static __device__ __forceinline__ unsigned short f2bf(float f) {
    __bf16 b = (__bf16)f;
    return __builtin_bit_cast(unsigned short, b);
}

// ---------------------------------------------------------------- zero
__global__ __launch_bounds__(256) void zero_k(int* __restrict__ cnt,
                                              float* __restrict__ pooled, int n)
{
    int i = blockIdx.x * 256 + threadIdx.x;
    if (i < n) cnt[i] = 0;
    if (i < GG * HH) pooled[i] = 0.f;
}

// ---------------------------------------------------------------- CSR build
__global__ __launch_bounds__(256) void count_k(const int* __restrict__ dst,
                                               int* __restrict__ cnt, int ne)
{
    int e = blockIdx.x * 256 + threadIdx.x;
    if (e < ne) atomicAdd(&cnt[dst[e]], 1);
}

__global__ __launch_bounds__(SB) void scan1_k(const int* __restrict__ cnt,
                                              int* __restrict__ rowptr,
                                              int* __restrict__ partial, int n)
{
    __shared__ int s[SB];
    const int t = threadIdx.x, g = blockIdx.x * SB + t;
    const int v = (g < n) ? cnt[g] : 0;
    s[t] = v; __syncthreads();
    for (int off = 1; off < SB; off <<= 1) {
        int a = (t >= off) ? s[t - off] : 0; __syncthreads();
        s[t] += a; __syncthreads();
    }
    if (g < n) rowptr[g] = s[t] - v;             // exclusive within block
    if (t == SB - 1) partial[blockIdx.x] = s[t]; // block total
}

__global__ __launch_bounds__(128) void scan2_k(int* __restrict__ partial, int nb)
{
    __shared__ int s[128];
    const int t = threadIdx.x;
    const int v = (t < nb) ? partial[t] : 0;
    s[t] = v; __syncthreads();
    for (int off = 1; off < 128; off <<= 1) {
        int a = (t >= off) ? s[t - off] : 0; __syncthreads();
        s[t] += a; __syncthreads();
    }
    if (t < nb) partial[t] = s[t] - v;           // exclusive block offsets
}

__global__ __launch_bounds__(SB) void scan3_k(int* __restrict__ rowptr,
                                              const int* __restrict__ partial,
                                              int n, int ne)
{
    int g = blockIdx.x * SB + threadIdx.x;
    if (g < n) rowptr[g] += partial[blockIdx.x];
    if (g == n - 1) rowptr[n] = ne;
}

// countdown-scatter: consumes cnt (ends all-zero), fills eidx with src ids
__global__ __launch_bounds__(256) void scatter_k(const int* __restrict__ src,
                                                 const int* __restrict__ dst,
                                                 const int* __restrict__ rowptr,
                                                 int* __restrict__ cnt,
                                                 int* __restrict__ eidx, int ne)
{
    int e = blockIdx.x * 256 + threadIdx.x;
    if (e < ne) {
        const int d = dst[e];
        const int off = atomicSub(&cnt[d], 1) - 1;
        eidx[rowptr[d] + off] = src[e];
    }
}

// ------------------------------------------- graph boundaries (batch sorted)
__global__ __launch_bounds__(256) void bound_k(const int* __restrict__ batch,
                                               int* __restrict__ bound, int n)
{
    const int g = threadIdx.x;   // 0..255
    int lo = 0, hi = n;
    while (lo < hi) { int m = (lo + hi) >> 1; if (batch[m] < g) lo = m + 1; else hi = m; }
    bound[g] = lo;
    if (g == 0) bound[GG] = n;
}

// ---------------------------------------------------- pack W to frag order
// slot = frag*64 + lane; frag = mb*4 + kb
// out[slot*8 + j] = bf16( W[(kb*32 + (lane>>4)*8 + j)*128 + mb*16 + (lane&15)] )
// This layout serves as A-frags of W^T (and equally B-frags of W).
__global__ __launch_bounds__(256) void packW_k(const float* __restrict__ W,
                                               __bf16* __restrict__ out)
{
    const int slot = blockIdx.x * 256 + threadIdx.x;   // 0..2047
    const int frag = slot >> 6, lane = slot & 63;
    const int mb = frag >> 2, kb = frag & 3;
    const int col = mb * 16 + (lane & 15);
    const int k0  = kb * 32 + (lane >> 4) * 8;
    bf16x8 v;
    #pragma unroll
    for (int j = 0; j < 8; ++j) v[j] = (__bf16)W[(k0 + j) * HH + col];
    *(bf16x8*)&out[slot * 8] = v;
}

// ------------------------------------------- layer0 scalar pull aggregation
__global__ __launch_bounds__(256) void agg0_k(const float* __restrict__ x,
                                              const int* __restrict__ rowptr,
                                              const int* __restrict__ eidx,
                                              float* __restrict__ z0, int n)
{
    int i = blockIdx.x * 256 + threadIdx.x;
    if (i < n) {
        float s = x[i];
        const int e = rowptr[i + 1];
        for (int j = rowptr[i]; j < e; ++j) s += x[eidx[j]];
        z0[i] = s;
    }
}

// ------------------------------------------- dense pull aggregation (bf16)
// z[n][:] = h[n][:] + sum_{s in in(n)} h[s][:]; wave per node, 2 cols/lane
static __device__ __forceinline__ void agg_body(
    const unsigned short* __restrict__ h, const int* __restrict__ rowptr,
    const int* __restrict__ eidx, unsigned short* __restrict__ z, int n)
{
    const int gw   = (blockIdx.x * 256 + threadIdx.x) >> 6;
    const int lane = threadIdx.x & 63;
    const int nw   = (gridDim.x * 256) >> 6;
    const unsigned int* h4 = (const unsigned int*)h;   // 2 bf16 per u32
    unsigned int* z4 = (unsigned int*)z;

    for (int node = gw; node < n; node += nw) {
        const int b = rowptr[node], e = rowptr[node + 1];
        const unsigned int su = h4[(size_t)node * 64 + lane];
        float a0 = bf2f(su & 0xffff), a1 = bf2f(su >> 16);
        float b0 = 0.f, b1 = 0.f, c0 = 0.f, c1 = 0.f, d0 = 0.f, d1 = 0.f;
        int j = b;
        for (; j + 3 < e; j += 4) {
            const unsigned int v0 = h4[(size_t)eidx[j]     * 64 + lane];
            const unsigned int v1 = h4[(size_t)eidx[j + 1] * 64 + lane];
            const unsigned int v2 = h4[(size_t)eidx[j + 2] * 64 + lane];
            const unsigned int v3 = h4[(size_t)eidx[j + 3] * 64 + lane];
            a0 += bf2f(v0 & 0xffff); a1 += bf2f(v0 >> 16);
            b0 += bf2f(v1 & 0xffff); b1 += bf2f(v1 >> 16);
            c0 += bf2f(v2 & 0xffff); c1 += bf2f(v2 >> 16);
            d0 += bf2f(v3 & 0xffff); d1 += bf2f(v3 >> 16);
        }
        for (; j < e; ++j) {
            const unsigned int v = h4[(size_t)eidx[j] * 64 + lane];
            a0 += bf2f(v & 0xffff); a1 += bf2f(v >> 16);
        }
        const float s0 = (a0 + b0) + (c0 + d0);
        const float s1 = (a1 + b1) + (c1 + d1);
        z4[(size_t)node * 64 + lane] = (unsigned int)f2bf(s0) | ((unsigned int)f2bf(s1) << 16);
    }
}
__global__ __launch_bounds__(256) void agg1_k(const unsigned short* h, const int* rowptr,
                                              const int* eidx, unsigned short* z, int n)
{ agg_body(h, rowptr, eidx, z, n); }
__global__ __launch_bounds__(256) void agg2_k(const unsigned short* h, const int* rowptr,
                                              const int* eidx, unsigned short* z, int n)
{ agg_body(h, rowptr, eidx, z, n); }

// ------------------------------------------------------------- fused MLP
// h = relu(z @ W1 + b1) @ W2 + b2, computed transposed:
//   t^T = W1^T @ z^T  (MFMA, A = packed W1^T frags, B = z rows as-loaded)
//   bounce t through wave-local swizzled LDS tile (bf16)
//   h^T = W2^T @ t^T  -> lane holds 4 consecutive h-cols of one node.
// Block: 4 waves x 32 nodes = 128 nodes. L0: t built directly from scalar z0.
template<int L0>
static __device__ __forceinline__ void mlp_body(
    const void* __restrict__ zin,               // L0: float[N] ; else ushort[N][128]
    const __bf16* __restrict__ Wp1, const float* __restrict__ b1,
    const __bf16* __restrict__ Wp2, const float* __restrict__ b2,
    const float* __restrict__ W1raw,            // L0 only: [128]
    unsigned short* __restrict__ hout, int n)
{
    __shared__ __bf16 Wl[16384];                // 32 KB (W1T then W2T; L0: W2T)
    __shared__ unsigned short tt[4][4096];      // 8 KB per-wave t-tile
    __shared__ float b1l[HH], b2l[HH], w1l[HH];

    const int t    = threadIdx.x;
    const int lane = t & 63, wv = t >> 6;
    const int l16  = lane & 15, lq = lane >> 4;
    const int r0    = blockIdx.x * 128 + wv * 32;
    const int nodeA = r0 + l16, nodeB = r0 + 16 + l16;
    const int rowA  = min(nodeA, n - 1), rowB = min(nodeB, n - 1);
    const int swz   = (l16 & 7) << 4;           // (node&7)<<4 ; node≡l16 (mod 8)

    {   // stage first W + biases
        const __bf16* Wfirst = L0 ? Wp2 : Wp1;
        #pragma unroll
        for (int i = 0; i < 8; ++i)
            *(int4*)&Wl[(i * 256 + t) * 8] = *(const int4*)&Wfirst[(i * 256 + t) * 8];
        if (t < HH) {
            b2l[t] = b2[t];
            b1l[t] = b1[t];
            if (L0) w1l[t] = W1raw[t];
        }
    }
    __syncthreads();

    unsigned short* tl = tt[wv];

    // ---- produce t-tile (32 nodes x 128 tcols, bf16, swizzled)
    if (L0) {
        const float* z0 = (const float*)zin;
        const float sA = z0[rowA], sB = z0[rowB];
        #pragma unroll
        for (int mt = 0; mt < 8; ++mt) {
            const f32x4 w  = *(const f32x4*)&w1l[mt * 16 + lq * 4];
            const f32x4 bb = *(const f32x4*)&b1l[mt * 16 + lq * 4];
            bf16x4 pa, pb;
            #pragma unroll
            for (int r = 0; r < 4; ++r) {
                pa[r] = (__bf16)fmaxf(fmaf(sA, w[r], bb[r]), 0.f);
                pb[r] = (__bf16)fmaxf(fmaf(sB, w[r], bb[r]), 0.f);
            }
            *(bf16x4*)((char*)tl + ((l16 * 256 + mt * 32 + lq * 8) ^ swz)) = pa;
            *(bf16x4*)((char*)tl + (((16 + l16) * 256 + mt * 32 + lq * 8) ^ swz)) = pb;
        }
    } else {
        const unsigned short* z = (const unsigned short*)zin;
        bf16x8 zfA[4], zfB[4];
        #pragma unroll
        for (int kb = 0; kb < 4; ++kb) {
            zfA[kb] = *(const bf16x8*)&z[(size_t)rowA * HH + kb * 32 + lq * 8];
            zfB[kb] = *(const bf16x8*)&z[(size_t)rowB * HH + kb * 32 + lq * 8];
        }
        f32x4 a1A[8], a1B[8];
        #pragma unroll
        for (int mt = 0; mt < 8; ++mt) {
            const f32x4 bb = *(const f32x4*)&b1l[mt * 16 + lq * 4];
            a1A[mt] = bb; a1B[mt] = bb;
        }
        #pragma unroll
        for (int mt = 0; mt < 8; ++mt)
            #pragma unroll
            for (int kb = 0; kb < 4; ++kb) {
                const bf16x8 wf = *(const bf16x8*)&Wl[((mt * 4 + kb) * 64 + lane) * 8];
                a1A[mt] = __builtin_amdgcn_mfma_f32_16x16x32_bf16(wf, zfA[kb], a1A[mt], 0, 0, 0);
                a1B[mt] = __builtin_amdgcn_mfma_f32_16x16x32_bf16(wf, zfB[kb], a1B[mt], 0, 0, 0);
            }
        #pragma unroll
        for (int mt = 0; mt < 8; ++mt) {
            bf16x4 pa, pb;
            #pragma unroll
            for (int r = 0; r < 4; ++r) {
                pa[r] = (__bf16)fmaxf(a1A[mt][r], 0.f);
                pb[r] = (__bf16)fmaxf(a1B[mt][r], 0.f);
            }
            *(bf16x4*)((char*)tl + ((l16 * 256 + mt * 32 + lq * 8) ^ swz)) = pa;
            *(bf16x4*)((char*)tl + (((16 + l16) * 256 + mt * 32 + lq * 8) ^ swz)) = pb;
        }
    }

    if (!L0) {                 // restage W2 (all waves done reading W1)
        __syncthreads();
        #pragma unroll
        for (int i = 0; i < 8; ++i)
            *(int4*)&Wl[(i * 256 + t) * 8] = *(const int4*)&Wp2[(i * 256 + t) * 8];
        __syncthreads();
    }

    // ---- MFMA2: h^T = W2^T @ t^T
    bf16x8 tfA[4], tfB[4];
    #pragma unroll
    for (int kb = 0; kb < 4; ++kb) {
        tfA[kb] = *(const bf16x8*)((char*)tl + ((l16 * 256 + kb * 64 + lq * 16) ^ swz));
        tfB[kb] = *(const bf16x8*)((char*)tl + (((16 + l16) * 256 + kb * 64 + lq * 16) ^ swz));
    }
    f32x4 a2A[8], a2B[8];
    #pragma unroll
    for (int mb = 0; mb < 8; ++mb) {
        const f32x4 bb = *(const f32x4*)&b2l[mb * 16 + lq * 4];
        a2A[mb] = bb; a2B[mb] = bb;
    }
    #pragma unroll
    for (int mb = 0; mb < 8; ++mb)
        #pragma unroll
        for (int kb = 0; kb < 4; ++kb) {
            const bf16x8 wf = *(const bf16x8*)&Wl[((mb * 4 + kb) * 64 + lane) * 8];
            a2A[mb] = __builtin_amdgcn_mfma_f32_16x16x32_bf16(wf, tfA[kb], a2A[mb], 0, 0, 0);
            a2B[mb] = __builtin_amdgcn_mfma_f32_16x16x32_bf16(wf, tfB[kb], a2B[mb], 0, 0, 0);
        }

    // ---- store h (bf16): lane holds cols mb*16+lq*4..+3 of its node
    if (nodeA < n) {
        #pragma unroll
        for (int mb = 0; mb < 8; ++mb) {
            bf16x4 p;
            #pragma unroll
            for (int r = 0; r < 4; ++r) p[r] = (__bf16)a2A[mb][r];
            *(bf16x4*)&hout[(size_t)nodeA * HH + mb * 16 + lq * 4] = p;
        }
    }
    if (nodeB < n) {
        #pragma unroll
        for (int mb = 0; mb < 8; ++mb) {
            bf16x4 p;
            #pragma unroll
            for (int r = 0; r < 4; ++r) p[r] = (__bf16)a2B[mb][r];
            *(bf16x4*)&hout[(size_t)nodeB * HH + mb * 16 + lq * 4] = p;
        }
    }
}

__global__ __launch_bounds__(256) void l0_k(const float* z0, const float* W1, const float* b1,
                                            const __bf16* Wp2, const float* b2,
                                            unsigned short* h, int n)
{ mlp_body<1>(z0, nullptr, b1, Wp2, b2, W1, h, n); }

__global__ __launch_bounds__(256) void mlp1_k(const unsigned short* z,
                                              const __bf16* Wp1, const float* b1,
                                              const __bf16* Wp2, const float* b2,
                                              unsigned short* h, int n)
{ mlp_body<0>(z, Wp1, b1, Wp2, b2, nullptr, h, n); }

__global__ __launch_bounds__(256) void mlp2_k(const unsigned short* z,
                                              const __bf16* Wp1, const float* b1,
                                              const __bf16* Wp2, const float* b2,
                                              unsigned short* h, int n)
{ mlp_body<0>(z, Wp1, b1, Wp2, b2, nullptr, h, n); }

// ------------------------------------------------------- segment pooling
// grid = GG * PSPLIT blocks, 1 wave each; lane = u32 channel-pair.
// Each block sums its slice of the graph's rows, one atomicAdd per channel.
__global__ __launch_bounds__(64) void pool_k(const unsigned short* __restrict__ h,
                                             const int* __restrict__ bound,
                                             float* __restrict__ pooled)
{
    const int g = blockIdx.x >> 4;            // graph (PSPLIT==16)
    const int s = blockIdx.x & (PSPLIT - 1);  // split
    const int t = threadIdx.x;                // 0..63
    const int rb = bound[g], re = bound[g + 1];
    const int len = re - rb;
    const int i0 = rb + (int)(((long)len * s) / PSPLIT);
    const int i1 = rb + (int)(((long)len * (s + 1)) / PSPLIT);
    const unsigned int* h4 = (const unsigned int*)h;

    float s0 = 0.f, s1 = 0.f, t0 = 0.f, t1 = 0.f;
    float u0 = 0.f, u1 = 0.f, v0 = 0.f, v1 = 0.f;
    int r = i0;
    for (; r + 3 < i1; r += 4) {
        const unsigned int a = h4[(size_t)r * 64 + t];
        const unsigned int b = h4[(size_t)(r + 1) * 64 + t];
        const unsigned int c = h4[(size_t)(r + 2) * 64 + t];
        const unsigned int d = h4[(size_t)(r + 3) * 64 + t];
        s0 += bf2f(a & 0xffff); s1 += bf2f(a >> 16);
        t0 += bf2f(b & 0xffff); t1 += bf2f(b >> 16);
        u0 += bf2f(c & 0xffff); u1 += bf2f(c >> 16);
        v0 += bf2f(d & 0xffff); v1 += bf2f(d >> 16);
    }
    for (; r < i1; ++r) {
        const unsigned int a = h4[(size_t)r * 64 + t];
        s0 += bf2f(a & 0xffff); s1 += bf2f(a >> 16);
    }
    const float r0 = (s0 + t0) + (u0 + v0);
    const float r1 = (s1 + t1) + (u1 + v1);
    if (i0 < i1) {
        unsafeAtomicAdd(&pooled[g * HH + t * 2 + 0], r0);
        unsafeAtomicAdd(&pooled[g * HH + t * 2 + 1], r1);
    }
}

// ---------------------------------------------------------------- final FC
__global__ __launch_bounds__(128) void fc_k(const float* __restrict__ pooled,
                                            const float* __restrict__ Wfc,
                                            const float* __restrict__ bfc,
                                            float* __restrict__ out)
{
    __shared__ float p[HH];
    const int g = blockIdx.x, k = threadIdx.x;
    p[k] = pooled[g * HH + k];
    __syncthreads();
    float acc = bfc[k];
    #pragma unroll 8
    for (int j = 0; j < HH; ++j) acc = fmaf(p[j], Wfc[j * HH + k], acc);
    out[g * HH + k] = acc;
}

extern "C" void kernel_launch(void* const* d_in, const int* in_sizes, int n_in,
                              void* d_out, int out_size, void* d_ws, size_t ws_size,
                              hipStream_t stream)
{
    const float* x     = (const float*)d_in[0];
    const int*   ei    = (const int*)d_in[1];
    const int*   batch = (const int*)d_in[2];
    const float* W1_0 = (const float*)d_in[3];
    const float* b1_0 = (const float*)d_in[4];
    const float* W2_0 = (const float*)d_in[5];
    const float* b2_0 = (const float*)d_in[6];
    const float* W1_1 = (const float*)d_in[7];
    const float* b1_1 = (const float*)d_in[8];
    const float* W2_1 = (const float*)d_in[9];
    const float* b2_1 = (const float*)d_in[10];
    const float* W1_2 = (const float*)d_in[11];
    const float* b1_2 = (const float*)d_in[12];
    const float* W2_2 = (const float*)d_in[13];
    const float* b2_2 = (const float*)d_in[14];
    const float* Wfc  = (const float*)d_in[15];
    const float* bfc  = (const float*)d_in[16];

    const int N = in_sizes[0];          // 100000
    const int E = in_sizes[1] / 2;      // 640000
    const int* src = ei;
    const int* dst = ei + E;

    // ---- workspace carve (256B aligned sections)
    char* p = (char*)d_ws;
    #define CARVE(ty, name, count) ty* name = (ty*)p; p += (((size_t)(count) * sizeof(ty)) + 255) & ~(size_t)255;
    CARVE(unsigned short, z,      (size_t)N * HH)
    CARVE(unsigned short, h,      (size_t)N * HH)
    CARVE(float,          z0,     N)
    CARVE(float,          pooled, GG * HH)
    CARVE(int,            rowptr, N + 1)
    CARVE(int,            cnt,    N)
    CARVE(int,            eidx,   E)
    CARVE(int,            partial,128)
    CARVE(int,            bound,  GG + 1)
    CARVE(__bf16,         Wp,     5 * 16384)
    #undef CARVE
    float* outp = (float*)d_out;

    const int nbs  = (N + SB - 1) / SB;   // scan blocks (98)
    const int gblk = (N + 127) / 128;     // mlp blocks (782)

    // ---- CSR build + graph bounds
    zero_k<<<(N + 255) / 256, 256, 0, stream>>>(cnt, pooled, N);
    count_k<<<(E + 255) / 256, 256, 0, stream>>>(dst, cnt, E);
    scan1_k<<<nbs, SB, 0, stream>>>(cnt, rowptr, partial, N);
    scan2_k<<<1, 128, 0, stream>>>(partial, nbs);
    scan3_k<<<nbs, SB, 0, stream>>>(rowptr, partial, N, E);
    scatter_k<<<(E + 255) / 256, 256, 0, stream>>>(src, dst, rowptr, cnt, eidx, E);
    bound_k<<<1, 256, 0, stream>>>(batch, bound, N);

    // ---- pack weights (frag order, bf16)
    packW_k<<<8, 256, 0, stream>>>(W2_0, Wp);
    packW_k<<<8, 256, 0, stream>>>(W1_1, Wp + 16384);
    packW_k<<<8, 256, 0, stream>>>(W2_1, Wp + 2 * 16384);
    packW_k<<<8, 256, 0, stream>>>(W1_2, Wp + 3 * 16384);
    packW_k<<<8, 256, 0, stream>>>(W2_2, Wp + 4 * 16384);

    // ---- layer 0
    agg0_k<<<(N + 255) / 256, 256, 0, stream>>>(x, rowptr, eidx, z0, N);
    l0_k<<<gblk, 256, 0, stream>>>(z0, W1_0, b1_0, Wp, b2_0, h, N);

    // ---- layer 1
    agg1_k<<<2048, 256, 0, stream>>>(h, rowptr, eidx, z, N);
    mlp1_k<<<gblk, 256, 0, stream>>>(z, Wp + 16384, b1_1, Wp + 2 * 16384, b2_1, h, N);

    // ---- layer 2
    agg2_k<<<2048, 256, 0, stream>>>(h, rowptr, eidx, z, N);
    mlp2_k<<<gblk, 256, 0, stream>>>(z, Wp + 3 * 16384, b1_2, Wp + 4 * 16384, b2_2, h, N);

    // ---- pool + FC
    pool_k<<<GG * PSPLIT, 64, 0, stream>>>(h, bound, pooled);
    fc_k<<<GG, HH, 0, stream>>>(pooled, Wfc, bfc, outp);
}